// Round 3
// baseline (503.877 us; speedup 1.0000x reference)
//
#include <hip/hip_runtime.h>
#include <hip/hip_bf16.h>
#include <cstddef>

#define H 200
#define NA 48
#define NBB 96
#define BATCH 128
#define AFD 39
#define BFD 50          // 39+11
#define LP 1000
#define CATD (AFD + H)  // 239
#define BPB 8           // bonds per block in message kernel
#define APB 8           // atoms per block in atom kernel
#define BIPB 4          // bonds per block in bond-input kernel

typedef unsigned short ushort_t;
typedef __bf16 bf16x8 __attribute__((ext_vector_type(8)));
typedef float f32x16 __attribute__((ext_vector_type(16)));

union U16B { uint4 u; bf16x8 b; };
static __device__ __forceinline__ bf16x8 as_bf16x8(uint4 u) { U16B x; x.u = u; return x.b; }

// float -> bf16 (RNE)
static __device__ __forceinline__ ushort_t f2bf(float f) {
    union { float f; unsigned u; } a; a.f = f;
    unsigned r = (a.u + 0x7FFFu + ((a.u >> 16) & 1u)) >> 16;
    return (ushort_t)r;
}

// ---------------- zero init ----------------
__global__ void k_zero(float* p, int n) {
    int i = blockIdx.x * blockDim.x + threadIdx.x;
    if (i < n) p[i] = 0.f;
}

// ---------------- weight swizzle to 32x32x16 A-fragment order ----------------
// Wb[((ct32*NS + s)*64 + lane)*8 + j] = bf16(w[co][ci][t])
//   co = ct32*32 + (lane&31), t = s/NC, cc = s%NC, ci = cc*16 + (lane>>5)*8 + j
template <int COUT, int CIN, int CP, int K, int NT32>
__global__ __launch_bounds__(256) void k_prep_w(
        const float* __restrict__ w, ushort_t* __restrict__ Wb) {
    constexpr int NC = CP / 16;
    constexpr int NS = K * NC;
    constexpr int TOT = NT32 * NS * 512;
    int tid = blockIdx.x * blockDim.x + threadIdx.x;
    if (tid >= TOT) return;
    int j = tid & 7;
    int lane = (tid >> 3) & 63;
    int s = (tid >> 9) % NS;
    int ct = (tid >> 9) / NS;
    int co = ct * 32 + (lane & 31);
    int t = s / NC, cc = s % NC;
    int ci = cc * 16 + ((lane >> 5) & 1) * 8 + j;
    float v = 0.f;
    if (co < COUT && ci < CIN) v = w[((size_t)co * CIN + ci) * K + t];
    Wb[tid] = f2bf(v);
}

// ---------------- protein embedding -> channel-last bf16 (B, L, 64) ----------------
__global__ __launch_bounds__(256) void k_embed_bf(
        const int* __restrict__ seq, const float* __restrict__ emb,
        ushort_t* __restrict__ act0) {
    int tid = blockIdx.x * blockDim.x + threadIdx.x;  // (b*L + l)*8 + chunk
    if (tid >= BATCH * LP * 8) return;
    int i = tid >> 3;
    int c0 = (tid & 7) * 8;
    int s = seq[i];
    const float* e = emb + (size_t)s * 50;
    ushort_t h[8];
#pragma unroll
    for (int j = 0; j < 8; ++j) {
        int c = c0 + j;
        h[j] = (c < 50) ? f2bf(e[c]) : (ushort_t)0;
    }
    uint4 o;
    o.x = (unsigned)h[0] | ((unsigned)h[1] << 16);
    o.y = (unsigned)h[2] | ((unsigned)h[3] << 16);
    o.z = (unsigned)h[4] | ((unsigned)h[5] << 16);
    o.w = (unsigned)h[6] | ((unsigned)h[7] << 16);
    *(uint4*)(act0 + (size_t)i * 64 + c0) = o;
}

// ---------------- MFMA conv1d, 32x32x16, 2x co register blocking ----------------
// in: (B, LP, CP) bf16, weights pre-swizzled. Wave = 64co x 128l.
// Block = CO_WAVES x L_WAVES waves (4 total).
// !FMAX: out (B, LP, COUT) bf16.  FMAX: relu+global max -> atomicMax xout[b*400+200+co].
template <int CP, int K, int COUT, int CO_WAVES, int L_WAVES, bool FMAX>
__global__ __launch_bounds__(256, 2) void k_conv_mfma(
        const ushort_t* __restrict__ act, const ushort_t* __restrict__ Wb,
        const float* __restrict__ bias, void* __restrict__ outv) {
    constexpr int NC = CP / 16;
    constexpr int NS = K * NC;
    constexpr int P = K / 2;
    constexpr int PITCH = CP + 8;       // ushorts; keeps rows 16B aligned, breaks pow2 stride
    constexpr int LTILE = 128 * L_WAVES;
    constexpr int ROWS = LTILE + K - 1;
    __shared__ __align__(16) ushort_t Xs[ROWS * PITCH];

    int b = blockIdx.z, lb = blockIdx.x;
    int l0 = lb * LTILE;
    int tid = threadIdx.x;

    // ---- stage X tile (halo, zero-padded at edges) ----
    constexpr int CPR = CP / 8;
    const ushort_t* actb = act + (size_t)b * LP * CP;
    for (int idx = tid; idx < ROWS * CPR; idx += 256) {
        int r = idx / CPR, c = idx % CPR;
        int l = l0 - P + r;
        uint4 v = {0u, 0u, 0u, 0u};
        if ((unsigned)l < (unsigned)LP) v = *(const uint4*)(actb + (size_t)l * CP + c * 8);
        *(uint4*)(Xs + r * PITCH + c * 8) = v;
    }

    int lane = tid & 63, wv = tid >> 6;
    int cw = wv % CO_WAVES;           // co-wave: covers co [cw*64, cw*64+64)
    int lw = wv / CO_WAVES;           // l-wave: covers l [lw*128, lw*128+128) within tile
    int ln31 = lane & 31, half = lane >> 5;
    int lwbase = lw * 128;

    // A stream base: fragment (ct32, s) at Wb + ((ct32*NS + s)*64 + lane)*8 ushorts
    const uint4* A0 = (const uint4*)Wb + ((size_t)(cw * 2) * NS) * 64 + lane;

    f32x16 acc[2][4];
#pragma unroll
    for (int ct = 0; ct < 2; ++ct)
#pragma unroll
        for (int lt = 0; lt < 4; ++lt)
#pragma unroll
            for (int r = 0; r < 16; ++r) acc[ct][lt][r] = 0.f;

    __syncthreads();

    // B fragment base (ushort index): row = lwbase + lt*32 + ln31, col = cc*16 + half*8
    int bbase = (lwbase + ln31) * PITCH + half * 8;

    for (int t = 0; t < K; ++t) {
        int btb = bbase + t * PITCH;
#pragma unroll 2
        for (int cc = 0; cc < NC; ++cc) {
            int s = t * NC + cc;
            uint4 a0 = A0[(size_t)s * 64];
            uint4 a1 = A0[(size_t)(NS + s) * 64];
#pragma unroll
            for (int lt = 0; lt < 4; ++lt) {
                uint4 bv = *(const uint4*)(Xs + btb + cc * 16 + lt * 32 * PITCH);
                acc[0][lt] = __builtin_amdgcn_mfma_f32_32x32x16_bf16(
                    as_bf16x8(a0), as_bf16x8(bv), acc[0][lt], 0, 0, 0);
                acc[1][lt] = __builtin_amdgcn_mfma_f32_32x32x16_bf16(
                    as_bf16x8(a1), as_bf16x8(bv), acc[1][lt], 0, 0, 0);
            }
        }
    }

    // C/D layout: col(l) = lane&31, row(co) = (r&3) + 8*(r>>2) + 4*half
    if (!FMAX) {
        ushort_t* out = (ushort_t*)outv + (size_t)b * LP * COUT;
#pragma unroll
        for (int ct = 0; ct < 2; ++ct) {
            int cbase = (cw * 2 + ct) * 32 + 4 * half;
#pragma unroll
            for (int g = 0; g < 4; ++g) {
                int co = cbase + 8 * g;
                if (co >= COUT) continue;
                float4 bv = *(const float4*)(bias + co);
#pragma unroll
                for (int lt = 0; lt < 4; ++lt) {
                    int l = l0 + lwbase + lt * 32 + ln31;
                    if (l < LP) {
                        ushort_t h0 = f2bf(fmaxf(acc[ct][lt][4 * g + 0] + bv.x, 0.f));
                        ushort_t h1 = f2bf(fmaxf(acc[ct][lt][4 * g + 1] + bv.y, 0.f));
                        ushort_t h2 = f2bf(fmaxf(acc[ct][lt][4 * g + 2] + bv.z, 0.f));
                        ushort_t h3 = f2bf(fmaxf(acc[ct][lt][4 * g + 3] + bv.w, 0.f));
                        uint2 o;
                        o.x = (unsigned)h0 | ((unsigned)h1 << 16);
                        o.y = (unsigned)h2 | ((unsigned)h3 << 16);
                        *(uint2*)(out + (size_t)l * COUT + co) = o;
                    }
                }
            }
        }
    } else {
        float* xout = (float*)outv;
#pragma unroll
        for (int ct = 0; ct < 2; ++ct) {
            float mx[16];
#pragma unroll
            for (int r = 0; r < 16; ++r) mx[r] = -3.0e38f;
#pragma unroll
            for (int lt = 0; lt < 4; ++lt) {
                int l = l0 + lwbase + lt * 32 + ln31;
                if (l < LP) {
#pragma unroll
                    for (int r = 0; r < 16; ++r) mx[r] = fmaxf(mx[r], acc[ct][lt][r]);
                }
            }
#pragma unroll
            for (int r = 0; r < 16; ++r) {
#pragma unroll
                for (int off = 1; off < 32; off <<= 1)
                    mx[r] = fmaxf(mx[r], __shfl_xor(mx[r], off, 64));
            }
            if (ln31 == 0) {
                int cbase = (cw * 2 + ct) * 32 + 4 * half;
#pragma unroll
                for (int r = 0; r < 16; ++r) {
                    int co = cbase + (r & 3) + 8 * (r >> 2);
                    if (co < COUT) {
                        float v = fmaxf(mx[r] + bias[co], 0.f);
                        atomicMax((int*)&xout[(size_t)b * 400 + 200 + co], __float_as_int(v));
                    }
                }
            }
        }
    }
}

// ---------------- binput = fbonds @ W_i ; msg = relu(binput) ----------------
__global__ __launch_bounds__(256) void k_bond_input(
        const float* __restrict__ fbonds, const float* __restrict__ Wi,
        float* __restrict__ binput, float* __restrict__ msg) {
    int bond0 = blockIdx.x * BIPB;
    __shared__ float fb[BIPB][BFD];
    int tid = threadIdx.x;
    if (tid < BIPB * BFD) fb[tid / BFD][tid % BFD] = fbonds[(size_t)bond0 * BFD + tid];
    __syncthreads();
    if (tid < H) {
        float acc[BIPB];
#pragma unroll
        for (int q = 0; q < BIPB; ++q) acc[q] = 0.f;
#pragma unroll 5
        for (int k = 0; k < BFD; ++k) {
            float w = Wi[k * H + tid];
#pragma unroll
            for (int q = 0; q < BIPB; ++q) acc[q] += fb[q][k] * w;
        }
#pragma unroll
        for (int q = 0; q < BIPB; ++q) {
            size_t o = (size_t)(bond0 + q) * H + tid;
            binput[o] = acc[q];
            msg[o] = fmaxf(acc[q], 0.f);
        }
    }
}

// ---------------- message update: msgOut = relu(binput + (sum nei) @ W_h) ----------------
__global__ __launch_bounds__(256) void k_msg(
        const float* __restrict__ msgIn, const float* __restrict__ binput,
        const int* __restrict__ bgraph, const float* __restrict__ Wh,
        float* __restrict__ msgOut) {
    const int grpPerMol = NBB / BPB;
    int b = blockIdx.x / grpPerMol;
    int grp = blockIdx.x % grpPerMol;
    int bond0 = grp * BPB;
    __shared__ int idxs[BPB * 6];
    __shared__ float nei[BPB][H];
    int tid = threadIdx.x;
    if (tid < BPB * 6) idxs[tid] = bgraph[((size_t)(b * NBB + bond0)) * 6 + tid];
    __syncthreads();
    if (tid < H) {
        const float* base = msgIn + (size_t)b * NBB * H;
#pragma unroll
        for (int q = 0; q < BPB; ++q) {
            float s = 0.f;
#pragma unroll
            for (int j = 0; j < 6; ++j) s += base[(size_t)idxs[q * 6 + j] * H + tid];
            nei[q][tid] = s;
        }
    }
    __syncthreads();
    if (tid < H) {
        float acc[BPB];
#pragma unroll
        for (int q = 0; q < BPB; ++q)
            acc[q] = binput[((size_t)(b * NBB + bond0 + q)) * H + tid];
#pragma unroll 2
        for (int hi = 0; hi < H; ++hi) {
            float w = Wh[hi * H + tid];
#pragma unroll
            for (int q = 0; q < BPB; ++q) acc[q] += nei[q][hi] * w;
        }
#pragma unroll
        for (int q = 0; q < BPB; ++q)
            msgOut[((size_t)(b * NBB + bond0 + q)) * H + tid] = fmaxf(acc[q], 0.f);
    }
}

// ---------------- atom head: relu(cat(fa, nei) @ W_o + b), mean -> x[:, :200] ----------------
__global__ __launch_bounds__(256) void k_atom(
        const float* __restrict__ msg, const float* __restrict__ fatoms,
        const int* __restrict__ agraph, const float* __restrict__ Wo,
        const float* __restrict__ Wob, float* __restrict__ x) {
    const int grpPerMol = NA / APB;
    int b = blockIdx.x / grpPerMol;
    int grp = blockIdx.x % grpPerMol;
    int atom0 = grp * APB;
    __shared__ int idxs[APB * 6];
    __shared__ float cat[APB][CATD];
    int tid = threadIdx.x;
    if (tid < APB * 6) idxs[tid] = agraph[((size_t)(b * NA + atom0)) * 6 + tid];
    for (int idx = tid; idx < APB * AFD; idx += 256) {
        int q = idx / AFD, c = idx % AFD;
        cat[q][c] = fatoms[((size_t)(b * NA + atom0 + q)) * AFD + c];
    }
    __syncthreads();
    if (tid < H) {
        const float* base = msg + (size_t)b * NBB * H;
#pragma unroll
        for (int q = 0; q < APB; ++q) {
            float s = 0.f;
#pragma unroll
            for (int j = 0; j < 6; ++j) s += base[(size_t)idxs[q * 6 + j] * H + tid];
            cat[q][AFD + tid] = s;
        }
    }
    __syncthreads();
    if (tid < H) {
        float bb = Wob[tid];
        float acc[APB];
#pragma unroll
        for (int q = 0; q < APB; ++q) acc[q] = bb;
#pragma unroll 2
        for (int k = 0; k < CATD; ++k) {
            float w = Wo[k * H + tid];
#pragma unroll
            for (int q = 0; q < APB; ++q) acc[q] += cat[q][k] * w;
        }
        float s = 0.f;
#pragma unroll
        for (int q = 0; q < APB; ++q) s += fmaxf(acc[q], 0.f);
        atomicAdd(&x[(size_t)b * 400 + tid], s * (1.f / NA));
    }
}

// ---------------- FC head ----------------
__global__ __launch_bounds__(256) void k_fc0(
        const float* __restrict__ x, const float* __restrict__ w,
        const float* __restrict__ bias, float* __restrict__ h1) {
    int b = blockIdx.x;
    __shared__ float xr[400];
    int tid = threadIdx.x;
    for (int i = tid; i < 400; i += 256) xr[i] = x[(size_t)b * 400 + i];
    __syncthreads();
    if (tid < 200) {
        float acc = bias[tid];
#pragma unroll 4
        for (int k = 0; k < 400; ++k) acc += xr[k] * w[k * 200 + tid];
        h1[(size_t)b * 200 + tid] = fmaxf(acc, 0.f);
    }
}
__global__ __launch_bounds__(128) void k_fc1(
        const float* __restrict__ h1, const float* __restrict__ w,
        const float* __restrict__ bias, float* __restrict__ h2) {
    int b = blockIdx.x;
    __shared__ float xr[200];
    int tid = threadIdx.x;
    for (int i = tid; i < 200; i += 128) xr[i] = h1[(size_t)b * 200 + i];
    __syncthreads();
    if (tid < 100) {
        float acc = bias[tid];
#pragma unroll 4
        for (int k = 0; k < 200; ++k) acc += xr[k] * w[k * 100 + tid];
        h2[(size_t)b * 100 + tid] = fmaxf(acc, 0.f);
    }
}
__global__ __launch_bounds__(128) void k_fc2(
        const float* __restrict__ h2, const float* __restrict__ w,
        const float* __restrict__ bias, float* __restrict__ out) {
    int b = blockIdx.x * blockDim.x + threadIdx.x;
    if (b < BATCH) {
        float acc = bias[0];
#pragma unroll 4
        for (int k = 0; k < 100; ++k) acc += h2[(size_t)b * 100 + k] * w[k];
        out[b] = acc;
    }
}

extern "C" void kernel_launch(void* const* d_in, const int* in_sizes, int n_in,
                              void* d_out, int out_size, void* d_ws, size_t ws_size,
                              hipStream_t stream) {
    const float* fatoms = (const float*)d_in[0];
    const float* fbonds = (const float*)d_in[1];
    const int* agraph = (const int*)d_in[2];
    const int* bgraph = (const int*)d_in[3];
    const int* seq = (const int*)d_in[4];
    const float* Wi = (const float*)d_in[5];
    const float* Wh = (const float*)d_in[6];
    const float* Wo = (const float*)d_in[7];
    const float* Wob = (const float*)d_in[8];
    const float* embp = (const float*)d_in[9];
    const float* c0w = (const float*)d_in[10];
    const float* c0b = (const float*)d_in[11];
    const float* c1w = (const float*)d_in[12];
    const float* c1b = (const float*)d_in[13];
    const float* c2w = (const float*)d_in[14];
    const float* c2b = (const float*)d_in[15];
    const float* fc0w = (const float*)d_in[16];
    const float* fc0b = (const float*)d_in[17];
    const float* fc1w = (const float*)d_in[18];
    const float* fc1b = (const float*)d_in[19];
    const float* fc2w = (const float*)d_in[20];
    const float* fc2b = (const float*)d_in[21];

    float* ws = (float*)d_ws;
    float* binput = ws;                    // 2457600
    float* msgA = binput + 2457600;        // 2457600
    float* msgB = msgA + 2457600;          // 2457600
    float* x = msgB + 2457600;             // 51200
    float* h1 = x + 51200;                 // 25600
    float* h2 = h1 + 25600;                // 12800
    ushort_t* u = (ushort_t*)(h2 + 12800); // bf16 region
    ushort_t* act0 = u;                    // 128000*64  = 8192000
    ushort_t* act1 = act0 + 8192000;       // 128000*96  = 12288000
    ushort_t* act2 = act1 + 12288000;      // 128000*128 = 16384000
    ushort_t* Wb0 = act2 + 16384000;       // 4*12*512  = 24576
    ushort_t* Wb1 = Wb0 + 24576;           // 4*30*512  = 61440
    ushort_t* Wb2 = Wb1 + 61440;           // 8*56*512  = 229376

    // x zeroed: k_atom accumulates cols 0..199, conv2 atomicMax cols 200..399.
    k_zero<<<(51200 + 255) / 256, 256, 0, stream>>>(x, 51200);

    // weight swizzles (32x32x16 A-fragment order)
    k_prep_w<96, 50, 64, 3, 4><<<(4 * 12 * 512 + 255) / 256, 256, 0, stream>>>(c0w, Wb0);
    k_prep_w<128, 96, 96, 5, 4><<<(4 * 30 * 512 + 255) / 256, 256, 0, stream>>>(c1w, Wb1);
    k_prep_w<200, 128, 128, 7, 8><<<(8 * 56 * 512 + 255) / 256, 256, 0, stream>>>(c2w, Wb2);

    // ---- MPNN ----
    k_bond_input<<<BATCH * NBB / BIPB, 256, 0, stream>>>(fbonds, Wi, binput, msgA);
    k_msg<<<BATCH * NBB / BPB, 256, 0, stream>>>(msgA, binput, bgraph, Wh, msgB);
    k_msg<<<BATCH * NBB / BPB, 256, 0, stream>>>(msgB, binput, bgraph, Wh, msgA);
    k_atom<<<BATCH * NA / APB, 256, 0, stream>>>(msgA, fatoms, agraph, Wo, Wob, x);

    // ---- protein tower (bf16 MFMA, 32x32x16) ----
    k_embed_bf<<<(BATCH * LP * 8 + 255) / 256, 256, 0, stream>>>(seq, embp, act0);
    // conv0: CP=64,K=3,COUT=96, block=128co x 256l
    k_conv_mfma<64, 3, 96, 2, 2, false><<<dim3(4, 1, BATCH), 256, 0, stream>>>(act0, Wb0, c0b, act1);
    // conv1: CP=96,K=5,COUT=128, block=128co x 256l
    k_conv_mfma<96, 5, 128, 2, 2, false><<<dim3(4, 1, BATCH), 256, 0, stream>>>(act1, Wb1, c1b, act2);
    // conv2: CP=128,K=7,COUT=200(pad 256), block=256co x 128l, fused relu+maxpool
    k_conv_mfma<128, 7, 200, 4, 1, true><<<dim3(8, 1, BATCH), 256, 0, stream>>>(act2, Wb2, c2b, x);

    // ---- FC head ----
    k_fc0<<<BATCH, 256, 0, stream>>>(x, fc0w, fc0b, h1);
    k_fc1<<<BATCH, 128, 0, stream>>>(h1, fc1w, fc1b, h2);
    k_fc2<<<1, 128, 0, stream>>>(h2, fc2w, fc2b, (float*)d_out);
}

// Round 4
// 425.081 us; speedup vs baseline: 1.1854x; 1.1854x over previous
//
#include <hip/hip_runtime.h>
#include <hip/hip_bf16.h>
#include <cstddef>

#define H 200
#define NA 48
#define NBB 96
#define BATCH 128
#define AFD 39
#define BFD 50          // 39+11
#define LP 1000
#define CATD (AFD + H)  // 239
#define BPB 4           // bonds per block in message kernel (R3 APB/BPB=8 spilled: VGPR=12, 98us)
#define APB 2           // atoms per block in atom kernel
#define BIPB 4          // bonds per block in bond-input kernel

typedef unsigned short ushort_t;
typedef __bf16 bf16x8 __attribute__((ext_vector_type(8)));
typedef float f32x16 __attribute__((ext_vector_type(16)));

union U16B { uint4 u; bf16x8 b; };
static __device__ __forceinline__ bf16x8 as_bf16x8(uint4 u) { U16B x; x.u = u; return x.b; }

// float -> bf16 (RNE)
static __device__ __forceinline__ ushort_t f2bf(float f) {
    union { float f; unsigned u; } a; a.f = f;
    unsigned r = (a.u + 0x7FFFu + ((a.u >> 16) & 1u)) >> 16;
    return (ushort_t)r;
}

// ---------------- fused prep: 3 weight swizzles (32x32x16 A-frag order) + zero x ----------------
// Wb[((ct32*NS + s)*64 + lane)*8 + j] = bf16(w[co][ci][t])
//   co = ct32*32 + (lane&31), t = s/NC, cc = s%NC, ci = cc*16 + (lane>>5)*8 + j
template <int COUT, int CIN, int CP, int K>
static __device__ __forceinline__ void prep_one(int t, const float* __restrict__ w,
                                                ushort_t* __restrict__ Wb) {
    constexpr int NC = CP / 16;
    constexpr int NS = K * NC;
    int j = t & 7;
    int lane = (t >> 3) & 63;
    int s = (t >> 9) % NS;
    int ct = (t >> 9) / NS;
    int co = ct * 32 + (lane & 31);
    int tt = s / NC, cc = s % NC;
    int ci = cc * 16 + ((lane >> 5) & 1) * 8 + j;
    float v = 0.f;
    if (co < COUT && ci < CIN) v = w[((size_t)co * CIN + ci) * K + tt];
    Wb[t] = f2bf(v);
}

#define PREP_T0 (4 * 12 * 512)            // conv0: 4 tiles x NS=12
#define PREP_T1 (PREP_T0 + 4 * 30 * 512)  // conv1: 4 tiles x NS=30
#define PREP_T2 (PREP_T1 + 8 * 56 * 512)  // conv2: 8 tiles x NS=56
#define PREP_T3 (PREP_T2 + 51200)         // zero x

__global__ __launch_bounds__(256) void k_prep_all(
        const float* __restrict__ c0w, const float* __restrict__ c1w,
        const float* __restrict__ c2w, float* __restrict__ x,
        ushort_t* __restrict__ Wb0, ushort_t* __restrict__ Wb1,
        ushort_t* __restrict__ Wb2) {
    int tid = blockIdx.x * 256 + threadIdx.x;
    if (tid < PREP_T0) prep_one<96, 50, 64, 3>(tid, c0w, Wb0);
    else if (tid < PREP_T1) prep_one<128, 96, 96, 5>(tid - PREP_T0, c1w, Wb1);
    else if (tid < PREP_T2) prep_one<200, 128, 128, 7>(tid - PREP_T1, c2w, Wb2);
    else if (tid < PREP_T3) x[tid - PREP_T2] = 0.f;
}

// ---------------- protein embedding -> channel-last bf16 (B, L, 64) ----------------
__global__ __launch_bounds__(256) void k_embed_bf(
        const int* __restrict__ seq, const float* __restrict__ emb,
        ushort_t* __restrict__ act0) {
    int tid = blockIdx.x * blockDim.x + threadIdx.x;  // (b*L + l)*8 + chunk
    if (tid >= BATCH * LP * 8) return;
    int i = tid >> 3;
    int c0 = (tid & 7) * 8;
    int s = seq[i];
    const float* e = emb + (size_t)s * 50;
    ushort_t h[8];
#pragma unroll
    for (int j = 0; j < 8; ++j) {
        int c = c0 + j;
        h[j] = (c < 50) ? f2bf(e[c]) : (ushort_t)0;
    }
    uint4 o;
    o.x = (unsigned)h[0] | ((unsigned)h[1] << 16);
    o.y = (unsigned)h[2] | ((unsigned)h[3] << 16);
    o.z = (unsigned)h[4] | ((unsigned)h[5] << 16);
    o.w = (unsigned)h[6] | ((unsigned)h[7] << 16);
    *(uint4*)(act0 + (size_t)i * 64 + c0) = o;
}

// ---------------- MFMA conv1d, 32x32x16, software-pipelined ----------------
// Wave = 64co(ct=2) x 64l(lt=2), acc=64 regs. Block = 4 waves = 2cw x 2lw = 128co x 128l.
// 1-deep prefetch of A (global/L2) and B (LDS) breaks load->MFMA dependency; (256,3)
// caps unified regs at ~170 -> 3 waves/SIMD for latency hiding.
template <int CP, int K, int COUT, bool FMAX>
__global__ __launch_bounds__(256, 3) void k_conv_mfma(
        const ushort_t* __restrict__ act, const ushort_t* __restrict__ Wb,
        const float* __restrict__ bias, void* __restrict__ outv) {
    constexpr int NC = CP / 16;
    constexpr int NS = K * NC;
    constexpr int P = K / 2;
    constexpr int PITCH = CP + 8;   // bytes multiple of 16; breaks pow2 bank stride
    constexpr int LTILE = 128;
    constexpr int ROWS = LTILE + K - 1;
    __shared__ __align__(16) ushort_t Xs[ROWS * PITCH];

    int b = blockIdx.z, coB = blockIdx.y, lb = blockIdx.x;
    int l0 = lb * LTILE;
    int tid = threadIdx.x;

    // ---- stage X tile (halo, zero-padded at edges) ----
    constexpr int CPR = CP / 8;
    const ushort_t* actb = act + (size_t)b * LP * CP;
    for (int idx = tid; idx < ROWS * CPR; idx += 256) {
        int r = idx / CPR, c = idx % CPR;
        int l = l0 - P + r;
        uint4 v = {0u, 0u, 0u, 0u};
        if ((unsigned)l < (unsigned)LP) v = *(const uint4*)(actb + (size_t)l * CP + c * 8);
        *(uint4*)(Xs + r * PITCH + c * 8) = v;
    }

    int lane = tid & 63, wv = tid >> 6;
    int cw = wv & 1, lw = wv >> 1;
    int ln31 = lane & 31, half = lane >> 5;

    // A stream: fragment (tile, s) at Wb + ((tile*NS + s)*64 + lane) uint4s
    const uint4* A0 = (const uint4*)Wb + ((size_t)(coB * 4 + cw * 2) * NS) * 64 + lane;
    // B base (ushort idx): row = lw*64 + lt*32 + ln31 + t, col = cc*16 + half*8
    int bbase = (lw * 64 + ln31) * PITCH + half * 8;

    f32x16 acc[2][2];
#pragma unroll
    for (int ct = 0; ct < 2; ++ct)
#pragma unroll
        for (int lt = 0; lt < 2; ++lt)
#pragma unroll
            for (int r = 0; r < 16; ++r) acc[ct][lt][r] = 0.f;

    __syncthreads();

    uint4 aC0 = A0[0];
    uint4 aC1 = A0[(size_t)NS * 64];
    uint4 bC0 = *(const uint4*)(Xs + bbase);
    uint4 bC1 = *(const uint4*)(Xs + bbase + 32 * PITCH);

#pragma unroll
    for (int s = 0; s < NS; ++s) {
        int sn = (s + 1 < NS) ? s + 1 : NS - 1;   // folds at compile time (full unroll)
        int tn = sn / NC, ccn = sn % NC;
        uint4 aN0 = A0[(size_t)sn * 64];
        uint4 aN1 = A0[(size_t)(NS + sn) * 64];
        int off = bbase + tn * PITCH + ccn * 16;
        uint4 bN0 = *(const uint4*)(Xs + off);
        uint4 bN1 = *(const uint4*)(Xs + off + 32 * PITCH);

        acc[0][0] = __builtin_amdgcn_mfma_f32_32x32x16_bf16(
            as_bf16x8(aC0), as_bf16x8(bC0), acc[0][0], 0, 0, 0);
        acc[1][0] = __builtin_amdgcn_mfma_f32_32x32x16_bf16(
            as_bf16x8(aC1), as_bf16x8(bC0), acc[1][0], 0, 0, 0);
        acc[0][1] = __builtin_amdgcn_mfma_f32_32x32x16_bf16(
            as_bf16x8(aC0), as_bf16x8(bC1), acc[0][1], 0, 0, 0);
        acc[1][1] = __builtin_amdgcn_mfma_f32_32x32x16_bf16(
            as_bf16x8(aC1), as_bf16x8(bC1), acc[1][1], 0, 0, 0);

        aC0 = aN0; aC1 = aN1; bC0 = bN0; bC1 = bN1;
    }

    // C/D layout: col(l) = lane&31, row(co) = (r&3) + 8*(r>>2) + 4*half
    if (!FMAX) {
        ushort_t* out = (ushort_t*)outv + (size_t)b * LP * COUT;
#pragma unroll
        for (int ct = 0; ct < 2; ++ct) {
            int cbase = coB * 128 + cw * 64 + ct * 32 + 4 * half;
#pragma unroll
            for (int g = 0; g < 4; ++g) {
                int co = cbase + 8 * g;
                if (co >= COUT) continue;
                float4 bv = *(const float4*)(bias + co);
#pragma unroll
                for (int lt = 0; lt < 2; ++lt) {
                    int l = l0 + lw * 64 + lt * 32 + ln31;
                    if (l < LP) {
                        ushort_t h0 = f2bf(fmaxf(acc[ct][lt][4 * g + 0] + bv.x, 0.f));
                        ushort_t h1 = f2bf(fmaxf(acc[ct][lt][4 * g + 1] + bv.y, 0.f));
                        ushort_t h2 = f2bf(fmaxf(acc[ct][lt][4 * g + 2] + bv.z, 0.f));
                        ushort_t h3 = f2bf(fmaxf(acc[ct][lt][4 * g + 3] + bv.w, 0.f));
                        uint2 o;
                        o.x = (unsigned)h0 | ((unsigned)h1 << 16);
                        o.y = (unsigned)h2 | ((unsigned)h3 << 16);
                        *(uint2*)(out + (size_t)l * COUT + co) = o;
                    }
                }
            }
        }
    } else {
        float* xout = (float*)outv;
#pragma unroll
        for (int ct = 0; ct < 2; ++ct) {
            float mx[16];
#pragma unroll
            for (int r = 0; r < 16; ++r) mx[r] = -3.0e38f;
#pragma unroll
            for (int lt = 0; lt < 2; ++lt) {
                int l = l0 + lw * 64 + lt * 32 + ln31;
                if (l < LP) {
#pragma unroll
                    for (int r = 0; r < 16; ++r) mx[r] = fmaxf(mx[r], acc[ct][lt][r]);
                }
            }
#pragma unroll
            for (int r = 0; r < 16; ++r) {
#pragma unroll
                for (int off = 1; off < 32; off <<= 1)
                    mx[r] = fmaxf(mx[r], __shfl_xor(mx[r], off, 64));
            }
            if (ln31 == 0) {
                int cbase = coB * 128 + cw * 64 + ct * 32 + 4 * half;
#pragma unroll
                for (int r = 0; r < 16; ++r) {
                    int co = cbase + (r & 3) + 8 * (r >> 2);
                    if (co < COUT) {
                        float v = fmaxf(mx[r] + bias[co], 0.f);
                        atomicMax((int*)&xout[(size_t)b * 400 + 200 + co], __float_as_int(v));
                    }
                }
            }
        }
    }
}

// ---------------- binput = fbonds @ W_i ; msg = relu(binput) ----------------
__global__ __launch_bounds__(256) void k_bond_input(
        const float* __restrict__ fbonds, const float* __restrict__ Wi,
        float* __restrict__ binput, float* __restrict__ msg) {
    int bond0 = blockIdx.x * BIPB;
    __shared__ float fb[BIPB][BFD];
    int tid = threadIdx.x;
    if (tid < BIPB * BFD) fb[tid / BFD][tid % BFD] = fbonds[(size_t)bond0 * BFD + tid];
    __syncthreads();
    if (tid < H) {
        float acc[BIPB];
#pragma unroll
        for (int q = 0; q < BIPB; ++q) acc[q] = 0.f;
#pragma unroll 5
        for (int k = 0; k < BFD; ++k) {
            float w = Wi[k * H + tid];
#pragma unroll
            for (int q = 0; q < BIPB; ++q) acc[q] += fb[q][k] * w;
        }
#pragma unroll
        for (int q = 0; q < BIPB; ++q) {
            size_t o = (size_t)(bond0 + q) * H + tid;
            binput[o] = acc[q];
            msg[o] = fmaxf(acc[q], 0.f);
        }
    }
}

// ---------------- message update: msgOut = relu(binput + (sum nei) @ W_h) ----------------
__global__ __launch_bounds__(256) void k_msg(
        const float* __restrict__ msgIn, const float* __restrict__ binput,
        const int* __restrict__ bgraph, const float* __restrict__ Wh,
        float* __restrict__ msgOut) {
    const int grpPerMol = NBB / BPB;
    int b = blockIdx.x / grpPerMol;
    int grp = blockIdx.x % grpPerMol;
    int bond0 = grp * BPB;
    __shared__ int idxs[BPB * 6];
    __shared__ float nei[BPB][H];
    int tid = threadIdx.x;
    if (tid < BPB * 6) idxs[tid] = bgraph[((size_t)(b * NBB + bond0)) * 6 + tid];
    __syncthreads();
    if (tid < H) {
        const float* base = msgIn + (size_t)b * NBB * H;
#pragma unroll
        for (int q = 0; q < BPB; ++q) {
            float s = 0.f;
#pragma unroll
            for (int j = 0; j < 6; ++j) s += base[(size_t)idxs[q * 6 + j] * H + tid];
            nei[q][tid] = s;
        }
    }
    __syncthreads();
    if (tid < H) {
        float acc[BPB];
#pragma unroll
        for (int q = 0; q < BPB; ++q)
            acc[q] = binput[((size_t)(b * NBB + bond0 + q)) * H + tid];
#pragma unroll 4
        for (int hi = 0; hi < H; ++hi) {
            float w = Wh[hi * H + tid];
#pragma unroll
            for (int q = 0; q < BPB; ++q) acc[q] += nei[q][hi] * w;
        }
#pragma unroll
        for (int q = 0; q < BPB; ++q)
            msgOut[((size_t)(b * NBB + bond0 + q)) * H + tid] = fmaxf(acc[q], 0.f);
    }
}

// ---------------- atom head: relu(cat(fa, nei) @ W_o + b), mean -> x[:, :200] ----------------
__global__ __launch_bounds__(256) void k_atom(
        const float* __restrict__ msg, const float* __restrict__ fatoms,
        const int* __restrict__ agraph, const float* __restrict__ Wo,
        const float* __restrict__ Wob, float* __restrict__ x) {
    const int grpPerMol = NA / APB;
    int b = blockIdx.x / grpPerMol;
    int grp = blockIdx.x % grpPerMol;
    int atom0 = grp * APB;
    __shared__ int idxs[APB * 6];
    __shared__ float cat[APB][CATD];
    int tid = threadIdx.x;
    if (tid < APB * 6) idxs[tid] = agraph[((size_t)(b * NA + atom0)) * 6 + tid];
    if (tid >= 64 && tid < 64 + APB * AFD) {
        int t = tid - 64;
        int q = t / AFD, c = t % AFD;
        cat[q][c] = fatoms[((size_t)(b * NA + atom0 + q)) * AFD + c];
    }
    __syncthreads();
    if (tid < H) {
        const float* base = msg + (size_t)b * NBB * H;
#pragma unroll
        for (int q = 0; q < APB; ++q) {
            float s = 0.f;
#pragma unroll
            for (int j = 0; j < 6; ++j) s += base[(size_t)idxs[q * 6 + j] * H + tid];
            cat[q][AFD + tid] = s;
        }
    }
    __syncthreads();
    if (tid < H) {
        float bb = Wob[tid];
        float acc0 = bb, acc1 = bb;
#pragma unroll 4
        for (int k = 0; k < CATD; ++k) {
            float w = Wo[k * H + tid];
            acc0 += cat[0][k] * w;
            acc1 += cat[1][k] * w;
        }
        atomicAdd(&x[(size_t)b * 400 + tid],
                  (fmaxf(acc0, 0.f) + fmaxf(acc1, 0.f)) * (1.f / NA));
    }
}

// ---------------- fused FC head: 400 -> 200 -> 100 -> 1 ----------------
__global__ __launch_bounds__(256) void k_fc(
        const float* __restrict__ x,
        const float* __restrict__ w0, const float* __restrict__ b0,
        const float* __restrict__ w1, const float* __restrict__ b1,
        const float* __restrict__ w2, const float* __restrict__ b2,
        float* __restrict__ out) {
    int b = blockIdx.x, tid = threadIdx.x;
    __shared__ float xr[400];
    __shared__ float h1[200];
    __shared__ float h2[100];
    for (int i = tid; i < 400; i += 256) xr[i] = x[(size_t)b * 400 + i];
    __syncthreads();
    if (tid < 200) {
        float a = b0[tid];
#pragma unroll 4
        for (int k = 0; k < 400; ++k) a += xr[k] * w0[k * 200 + tid];
        h1[tid] = fmaxf(a, 0.f);
    }
    __syncthreads();
    if (tid < 100) {
        float a = b1[tid];
#pragma unroll 4
        for (int k = 0; k < 200; ++k) a += h1[k] * w1[k * 100 + tid];
        h2[tid] = fmaxf(a, 0.f);
    }
    __syncthreads();
    if (tid == 0) {
        float a = b2[0];
#pragma unroll 4
        for (int k = 0; k < 100; ++k) a += h2[k] * w2[k];
        out[b] = a;
    }
}

extern "C" void kernel_launch(void* const* d_in, const int* in_sizes, int n_in,
                              void* d_out, int out_size, void* d_ws, size_t ws_size,
                              hipStream_t stream) {
    const float* fatoms = (const float*)d_in[0];
    const float* fbonds = (const float*)d_in[1];
    const int* agraph = (const int*)d_in[2];
    const int* bgraph = (const int*)d_in[3];
    const int* seq = (const int*)d_in[4];
    const float* Wi = (const float*)d_in[5];
    const float* Wh = (const float*)d_in[6];
    const float* Wo = (const float*)d_in[7];
    const float* Wob = (const float*)d_in[8];
    const float* embp = (const float*)d_in[9];
    const float* c0w = (const float*)d_in[10];
    const float* c0b = (const float*)d_in[11];
    const float* c1w = (const float*)d_in[12];
    const float* c1b = (const float*)d_in[13];
    const float* c2w = (const float*)d_in[14];
    const float* c2b = (const float*)d_in[15];
    const float* fc0w = (const float*)d_in[16];
    const float* fc0b = (const float*)d_in[17];
    const float* fc1w = (const float*)d_in[18];
    const float* fc1b = (const float*)d_in[19];
    const float* fc2w = (const float*)d_in[20];
    const float* fc2b = (const float*)d_in[21];

    float* ws = (float*)d_ws;
    float* binput = ws;                    // 2457600
    float* msgA = binput + 2457600;        // 2457600
    float* msgB = msgA + 2457600;          // 2457600
    float* x = msgB + 2457600;             // 51200
    ushort_t* u = (ushort_t*)(x + 51200);  // bf16 region
    ushort_t* act0 = u;                    // 128000*64  = 8192000
    ushort_t* act1 = act0 + 8192000;       // 128000*96  = 12288000
    ushort_t* act2 = act1 + 12288000;      // 128000*128 = 16384000
    ushort_t* Wb0 = act2 + 16384000;       // 4*12*512  = 24576
    ushort_t* Wb1 = Wb0 + 24576;           // 4*30*512  = 61440
    ushort_t* Wb2 = Wb1 + 61440;           // 8*56*512  = 229376

    // fused: weight swizzles + zero x (k_atom atomicAdd / conv2 atomicMax need zeros)
    k_prep_all<<<(PREP_T3 + 255) / 256, 256, 0, stream>>>(c0w, c1w, c2w, x, Wb0, Wb1, Wb2);

    // ---- MPNN ----
    k_bond_input<<<BATCH * NBB / BIPB, 256, 0, stream>>>(fbonds, Wi, binput, msgA);
    k_msg<<<BATCH * NBB / BPB, 256, 0, stream>>>(msgA, binput, bgraph, Wh, msgB);
    k_msg<<<BATCH * NBB / BPB, 256, 0, stream>>>(msgB, binput, bgraph, Wh, msgA);
    k_atom<<<BATCH * NA / APB, 256, 0, stream>>>(msgA, fatoms, agraph, Wo, Wob, x);

    // ---- protein tower (bf16 MFMA, 32x32x16, pipelined) ----
    k_embed_bf<<<(BATCH * LP * 8 + 255) / 256, 256, 0, stream>>>(seq, embp, act0);
    k_conv_mfma<64, 3, 96, false><<<dim3(8, 1, BATCH), 256, 0, stream>>>(act0, Wb0, c0b, act1);
    k_conv_mfma<96, 5, 128, false><<<dim3(8, 1, BATCH), 256, 0, stream>>>(act1, Wb1, c1b, act2);
    k_conv_mfma<128, 7, 200, true><<<dim3(8, 2, BATCH), 256, 0, stream>>>(act2, Wb2, c2b, x);

    // ---- fused FC head ----
    k_fc<<<BATCH, 256, 0, stream>>>(x, fc0w, fc0b, fc1w, fc1b, fc2w, fc2b, (float*)d_out);
}

// Round 5
// 413.130 us; speedup vs baseline: 1.2197x; 1.0289x over previous
//
#include <hip/hip_runtime.h>
#include <hip/hip_bf16.h>
#include <cstddef>

#define H 200
#define NA 48
#define NBB 96
#define BATCH 128
#define AFD 39
#define BFD 50          // 39+11
#define LP 1000
#define CATD (AFD + H)  // 239
#define BPB 4           // bonds per block in message kernel (APB/BPB=8 spilled in R3)
#define APB 2           // atoms per block in atom kernel
#define BIPB 4          // bonds per block in bond-input kernel

typedef unsigned short ushort_t;
typedef __bf16 bf16x8 __attribute__((ext_vector_type(8)));
typedef float f32x16 __attribute__((ext_vector_type(16)));

union U16B { uint4 u; bf16x8 b; };
static __device__ __forceinline__ bf16x8 as_bf16x8(uint4 u) { U16B x; x.u = u; return x.b; }

// float -> bf16 (RNE)
static __device__ __forceinline__ ushort_t f2bf(float f) {
    union { float f; unsigned u; } a; a.f = f;
    unsigned r = (a.u + 0x7FFFu + ((a.u >> 16) & 1u)) >> 16;
    return (ushort_t)r;
}

// ---------------- fused prep: 3 weight swizzles (32x32x16 A-frag order) + zero x ----------------
// Wb[((tile*NS + s)*64 + lane)*8 + j] = bf16(w[co][ci][t])
//   co = tile*32 + (lane&31), t = s/NC, cc = s%NC, ci = cc*16 + (lane>>5)*8 + j
template <int COUT, int CIN, int CP, int K>
static __device__ __forceinline__ void prep_one(int t, const float* __restrict__ w,
                                                ushort_t* __restrict__ Wb) {
    constexpr int NC = CP / 16;
    constexpr int NS = K * NC;
    int j = t & 7;
    int lane = (t >> 3) & 63;
    int s = (t >> 9) % NS;
    int ct = (t >> 9) / NS;
    int co = ct * 32 + (lane & 31);
    int tt = s / NC, cc = s % NC;
    int ci = cc * 16 + ((lane >> 5) & 1) * 8 + j;
    float v = 0.f;
    if (co < COUT && ci < CIN) v = w[((size_t)co * CIN + ci) * K + tt];
    Wb[t] = f2bf(v);
}

#define PREP_T0 (4 * 12 * 512)            // conv0: 4 tiles x NS=12
#define PREP_T1 (PREP_T0 + 4 * 30 * 512)  // conv1: 4 tiles x NS=30
#define PREP_T2 (PREP_T1 + 8 * 56 * 512)  // conv2: 8 tiles x NS=56
#define PREP_T3 (PREP_T2 + 51200)         // zero x

__global__ __launch_bounds__(256) void k_prep_all(
        const float* __restrict__ c0w, const float* __restrict__ c1w,
        const float* __restrict__ c2w, float* __restrict__ x,
        ushort_t* __restrict__ Wb0, ushort_t* __restrict__ Wb1,
        ushort_t* __restrict__ Wb2) {
    int tid = blockIdx.x * 256 + threadIdx.x;
    if (tid < PREP_T0) prep_one<96, 50, 64, 3>(tid, c0w, Wb0);
    else if (tid < PREP_T1) prep_one<128, 96, 96, 5>(tid - PREP_T0, c1w, Wb1);
    else if (tid < PREP_T2) prep_one<200, 128, 128, 7>(tid - PREP_T1, c2w, Wb2);
    else if (tid < PREP_T3) x[tid - PREP_T2] = 0.f;
}

// ---------------- MFMA conv1d body, 32x32x16, software-pipelined ----------------
// Wave = 64co(ct=2) x 64l(lt=2), acc=64 regs. Block = CO_WAVES x L_WAVES waves.
// EMB: build X tile directly from seq+emb (conv0 — no act0 buffer).
// FMAX: relu + global max over l -> atomicMax into xout[b*400+200+co].
template <int CP, int K, int COUT, int CO_WAVES, int L_WAVES, bool FMAX, bool EMB>
static __device__ __forceinline__ void conv_body(
        const ushort_t* __restrict__ act, const int* __restrict__ seq,
        const float* __restrict__ emb, const ushort_t* __restrict__ Wb,
        const float* __restrict__ bias, void* __restrict__ outv,
        ushort_t* __restrict__ Xs) {
    constexpr int NC = CP / 16;
    constexpr int NS = K * NC;
    constexpr int P = K / 2;
    constexpr int PITCH = CP + 8;     // ushorts; 16B-aligned rows, non-pow2 bank stride
    constexpr int LTILE = 64 * L_WAVES;
    constexpr int ROWS = LTILE + K - 1;
    constexpr int CPR = CP / 8;

    int b = blockIdx.z, lb = blockIdx.x;
    int l0 = lb * LTILE;
    int tid = threadIdx.x;

    // ---- stage X tile (halo, zero-padded at edges) ----
    if (EMB) {
        const int* seqb = seq + (size_t)b * LP;
        for (int idx = tid; idx < ROWS * CPR; idx += 256) {
            int r = idx / CPR, c = idx % CPR;
            int l = l0 - P + r;
            uint4 v = {0u, 0u, 0u, 0u};
            if ((unsigned)l < (unsigned)LP) {
                int s = seqb[l];
                const float* e = emb + (size_t)s * 50;
                ushort_t h[8];
#pragma unroll
                for (int j = 0; j < 8; ++j) {
                    int cc = c * 8 + j;
                    h[j] = (cc < 50) ? f2bf(e[cc]) : (ushort_t)0;
                }
                v.x = (unsigned)h[0] | ((unsigned)h[1] << 16);
                v.y = (unsigned)h[2] | ((unsigned)h[3] << 16);
                v.z = (unsigned)h[4] | ((unsigned)h[5] << 16);
                v.w = (unsigned)h[6] | ((unsigned)h[7] << 16);
            }
            *(uint4*)(Xs + r * PITCH + c * 8) = v;
        }
    } else {
        const ushort_t* actb = act + (size_t)b * LP * CP;
        for (int idx = tid; idx < ROWS * CPR; idx += 256) {
            int r = idx / CPR, c = idx % CPR;
            int l = l0 - P + r;
            uint4 v = {0u, 0u, 0u, 0u};
            if ((unsigned)l < (unsigned)LP) v = *(const uint4*)(actb + (size_t)l * CP + c * 8);
            *(uint4*)(Xs + r * PITCH + c * 8) = v;
        }
    }

    int lane = tid & 63, wv = tid >> 6;
    int cw = wv % CO_WAVES, lw = wv / CO_WAVES;
    int ln31 = lane & 31, half = lane >> 5;

    // A stream: fragment (tile, s) at Wb + ((tile*NS + s)*64 + lane) uint4s
    const uint4* A0 = (const uint4*)Wb + ((size_t)(cw * 2) * NS) * 64 + lane;
    // B base (ushort idx): row = lw*64 + lt*32 + ln31 + t, col = cc*16 + half*8
    int bbase = (lw * 64 + ln31) * PITCH + half * 8;

    f32x16 acc[2][2];
#pragma unroll
    for (int ct = 0; ct < 2; ++ct)
#pragma unroll
        for (int lt = 0; lt < 2; ++lt)
#pragma unroll
            for (int r = 0; r < 16; ++r) acc[ct][lt][r] = 0.f;

    __syncthreads();

    uint4 aC0 = A0[0];
    uint4 aC1 = A0[(size_t)NS * 64];
    uint4 bC0 = *(const uint4*)(Xs + bbase);
    uint4 bC1 = *(const uint4*)(Xs + bbase + 32 * PITCH);

#pragma unroll
    for (int s = 0; s < NS; ++s) {
        int sn = (s + 1 < NS) ? s + 1 : NS - 1;   // folds at compile time (full unroll)
        int tn = sn / NC, ccn = sn % NC;
        uint4 aN0 = A0[(size_t)sn * 64];
        uint4 aN1 = A0[(size_t)(NS + sn) * 64];
        int off = bbase + tn * PITCH + ccn * 16;
        uint4 bN0 = *(const uint4*)(Xs + off);
        uint4 bN1 = *(const uint4*)(Xs + off + 32 * PITCH);

        acc[0][0] = __builtin_amdgcn_mfma_f32_32x32x16_bf16(
            as_bf16x8(aC0), as_bf16x8(bC0), acc[0][0], 0, 0, 0);
        acc[1][0] = __builtin_amdgcn_mfma_f32_32x32x16_bf16(
            as_bf16x8(aC1), as_bf16x8(bC0), acc[1][0], 0, 0, 0);
        acc[0][1] = __builtin_amdgcn_mfma_f32_32x32x16_bf16(
            as_bf16x8(aC0), as_bf16x8(bC1), acc[0][1], 0, 0, 0);
        acc[1][1] = __builtin_amdgcn_mfma_f32_32x32x16_bf16(
            as_bf16x8(aC1), as_bf16x8(bC1), acc[1][1], 0, 0, 0);

        aC0 = aN0; aC1 = aN1; bC0 = bN0; bC1 = bN1;
    }

    // C/D layout: col(l) = lane&31, row(co within tile) = (r&3) + 8*(r>>2) + 4*half
    if (!FMAX) {
        ushort_t* out = (ushort_t*)outv + (size_t)b * LP * COUT;
#pragma unroll
        for (int ct = 0; ct < 2; ++ct) {
            int cbase = (cw * 2 + ct) * 32 + 4 * half;
#pragma unroll
            for (int g = 0; g < 4; ++g) {
                int co = cbase + 8 * g;
                if (co >= COUT) continue;
                float4 bv = *(const float4*)(bias + co);
#pragma unroll
                for (int lt = 0; lt < 2; ++lt) {
                    int l = l0 + lw * 64 + lt * 32 + ln31;
                    if (l < LP) {
                        ushort_t h0 = f2bf(fmaxf(acc[ct][lt][4 * g + 0] + bv.x, 0.f));
                        ushort_t h1 = f2bf(fmaxf(acc[ct][lt][4 * g + 1] + bv.y, 0.f));
                        ushort_t h2 = f2bf(fmaxf(acc[ct][lt][4 * g + 2] + bv.z, 0.f));
                        ushort_t h3 = f2bf(fmaxf(acc[ct][lt][4 * g + 3] + bv.w, 0.f));
                        uint2 o;
                        o.x = (unsigned)h0 | ((unsigned)h1 << 16);
                        o.y = (unsigned)h2 | ((unsigned)h3 << 16);
                        *(uint2*)(out + (size_t)l * COUT + co) = o;
                    }
                }
            }
        }
    } else {
        float* xout = (float*)outv;
#pragma unroll
        for (int ct = 0; ct < 2; ++ct) {
            float mx[16];
#pragma unroll
            for (int r = 0; r < 16; ++r) mx[r] = -3.0e38f;
#pragma unroll
            for (int lt = 0; lt < 2; ++lt) {
                int l = l0 + lw * 64 + lt * 32 + ln31;
                if (l < LP) {
#pragma unroll
                    for (int r = 0; r < 16; ++r) mx[r] = fmaxf(mx[r], acc[ct][lt][r]);
                }
            }
#pragma unroll
            for (int r = 0; r < 16; ++r) {
#pragma unroll
                for (int off = 1; off < 32; off <<= 1)
                    mx[r] = fmaxf(mx[r], __shfl_xor(mx[r], off, 64));
            }
            if (ln31 == 0) {
                int cbase = (cw * 2 + ct) * 32 + 4 * half;
#pragma unroll
                for (int r = 0; r < 16; ++r) {
                    int co = cbase + (r & 3) + 8 * (r >> 2);
                    if (co < COUT) {
                        float v = fmaxf(mx[r] + bias[co], 0.f);
                        atomicMax((int*)&xout[(size_t)b * 400 + 200 + co], __float_as_int(v));
                    }
                }
            }
        }
    }
}

// Distinct names so rocprof disambiguates the tower.
__global__ __launch_bounds__(256, 3) void k_conv0(
        const int* __restrict__ seq, const float* __restrict__ emb,
        const ushort_t* __restrict__ Wb, const float* __restrict__ bias,
        ushort_t* __restrict__ out) {
    __shared__ __align__(16) ushort_t Xs[(128 + 2) * (64 + 8)];
    conv_body<64, 3, 96, 2, 2, false, true>(nullptr, seq, emb, Wb, bias, out, Xs);
}
__global__ __launch_bounds__(256, 3) void k_conv1(
        const ushort_t* __restrict__ act, const ushort_t* __restrict__ Wb,
        const float* __restrict__ bias, ushort_t* __restrict__ out) {
    __shared__ __align__(16) ushort_t Xs[(128 + 4) * (96 + 8)];
    conv_body<96, 5, 128, 2, 2, false, false>(act, nullptr, nullptr, Wb, bias, out, Xs);
}
__global__ __launch_bounds__(256, 3) void k_conv2(
        const ushort_t* __restrict__ act, const ushort_t* __restrict__ Wb,
        const float* __restrict__ bias, float* __restrict__ x) {
    __shared__ __align__(16) ushort_t Xs[(64 + 6) * (128 + 8)];
    conv_body<128, 7, 200, 4, 1, true, false>(act, nullptr, nullptr, Wb, bias, x, Xs);
}

// ---------------- binput = fbonds @ W_i ; msg = relu(binput) ----------------
__global__ __launch_bounds__(256) void k_bond_input(
        const float* __restrict__ fbonds, const float* __restrict__ Wi,
        float* __restrict__ binput, float* __restrict__ msg) {
    int bond0 = blockIdx.x * BIPB;
    __shared__ float fb[BIPB][BFD];
    int tid = threadIdx.x;
    if (tid < BIPB * BFD) fb[tid / BFD][tid % BFD] = fbonds[(size_t)bond0 * BFD + tid];
    __syncthreads();
    if (tid < H) {
        float acc[BIPB];
#pragma unroll
        for (int q = 0; q < BIPB; ++q) acc[q] = 0.f;
#pragma unroll 5
        for (int k = 0; k < BFD; ++k) {
            float w = Wi[k * H + tid];
#pragma unroll
            for (int q = 0; q < BIPB; ++q) acc[q] += fb[q][k] * w;
        }
#pragma unroll
        for (int q = 0; q < BIPB; ++q) {
            size_t o = (size_t)(bond0 + q) * H + tid;
            binput[o] = acc[q];
            msg[o] = fmaxf(acc[q], 0.f);
        }
    }
}

// ---------------- message update: msgOut = relu(binput + (sum nei) @ W_h) ----------------
__global__ __launch_bounds__(256) void k_msg(
        const float* __restrict__ msgIn, const float* __restrict__ binput,
        const int* __restrict__ bgraph, const float* __restrict__ Wh,
        float* __restrict__ msgOut) {
    const int grpPerMol = NBB / BPB;
    int b = blockIdx.x / grpPerMol;
    int grp = blockIdx.x % grpPerMol;
    int bond0 = grp * BPB;
    __shared__ int idxs[BPB * 6];
    __shared__ float nei[BPB][H];
    int tid = threadIdx.x;
    if (tid < BPB * 6) idxs[tid] = bgraph[((size_t)(b * NBB + bond0)) * 6 + tid];
    __syncthreads();
    if (tid < H) {
        const float* base = msgIn + (size_t)b * NBB * H;
#pragma unroll
        for (int q = 0; q < BPB; ++q) {
            float s = 0.f;
#pragma unroll
            for (int j = 0; j < 6; ++j) s += base[(size_t)idxs[q * 6 + j] * H + tid];
            nei[q][tid] = s;
        }
    }
    __syncthreads();
    if (tid < H) {
        float acc[BPB];
#pragma unroll
        for (int q = 0; q < BPB; ++q)
            acc[q] = binput[((size_t)(b * NBB + bond0 + q)) * H + tid];
#pragma unroll 4
        for (int hi = 0; hi < H; ++hi) {
            float w = Wh[hi * H + tid];
#pragma unroll
            for (int q = 0; q < BPB; ++q) acc[q] += nei[q][hi] * w;
        }
#pragma unroll
        for (int q = 0; q < BPB; ++q)
            msgOut[((size_t)(b * NBB + bond0 + q)) * H + tid] = fmaxf(acc[q], 0.f);
    }
}

// ---------------- atom head: relu(cat(fa, nei) @ W_o + b), mean -> x[:, :200] ----------------
__global__ __launch_bounds__(256) void k_atom(
        const float* __restrict__ msg, const float* __restrict__ fatoms,
        const int* __restrict__ agraph, const float* __restrict__ Wo,
        const float* __restrict__ Wob, float* __restrict__ x) {
    const int grpPerMol = NA / APB;
    int b = blockIdx.x / grpPerMol;
    int grp = blockIdx.x % grpPerMol;
    int atom0 = grp * APB;
    __shared__ int idxs[APB * 6];
    __shared__ float cat[APB][CATD];
    int tid = threadIdx.x;
    if (tid < APB * 6) idxs[tid] = agraph[((size_t)(b * NA + atom0)) * 6 + tid];
    if (tid >= 64 && tid < 64 + APB * AFD) {
        int t = tid - 64;
        int q = t / AFD, c = t % AFD;
        cat[q][c] = fatoms[((size_t)(b * NA + atom0 + q)) * AFD + c];
    }
    __syncthreads();
    if (tid < H) {
        const float* base = msg + (size_t)b * NBB * H;
#pragma unroll
        for (int q = 0; q < APB; ++q) {
            float s = 0.f;
#pragma unroll
            for (int j = 0; j < 6; ++j) s += base[(size_t)idxs[q * 6 + j] * H + tid];
            cat[q][AFD + tid] = s;
        }
    }
    __syncthreads();
    if (tid < H) {
        float bb = Wob[tid];
        float acc0 = bb, acc1 = bb;
#pragma unroll 4
        for (int k = 0; k < CATD; ++k) {
            float w = Wo[k * H + tid];
            acc0 += cat[0][k] * w;
            acc1 += cat[1][k] * w;
        }
        atomicAdd(&x[(size_t)b * 400 + tid],
                  (fmaxf(acc0, 0.f) + fmaxf(acc1, 0.f)) * (1.f / NA));
    }
}

// ---------------- fused FC head: 400 -> 200 -> 100 -> 1 ----------------
__global__ __launch_bounds__(256) void k_fc(
        const float* __restrict__ x,
        const float* __restrict__ w0, const float* __restrict__ b0,
        const float* __restrict__ w1, const float* __restrict__ b1,
        const float* __restrict__ w2, const float* __restrict__ b2,
        float* __restrict__ out) {
    int b = blockIdx.x, tid = threadIdx.x;
    __shared__ float xr[400];
    __shared__ float h1[200];
    __shared__ float h2[100];
    for (int i = tid; i < 400; i += 256) xr[i] = x[(size_t)b * 400 + i];
    __syncthreads();
    if (tid < 200) {
        float a = b0[tid];
#pragma unroll 4
        for (int k = 0; k < 400; ++k) a += xr[k] * w0[k * 200 + tid];
        h1[tid] = fmaxf(a, 0.f);
    }
    __syncthreads();
    if (tid < 100) {
        float a = b1[tid];
#pragma unroll 4
        for (int k = 0; k < 200; ++k) a += h1[k] * w1[k * 100 + tid];
        h2[tid] = fmaxf(a, 0.f);
    }
    __syncthreads();
    if (tid == 0) {
        float a = b2[0];
#pragma unroll 4
        for (int k = 0; k < 100; ++k) a += h2[k] * w2[k];
        out[b] = a;
    }
}

extern "C" void kernel_launch(void* const* d_in, const int* in_sizes, int n_in,
                              void* d_out, int out_size, void* d_ws, size_t ws_size,
                              hipStream_t stream) {
    const float* fatoms = (const float*)d_in[0];
    const float* fbonds = (const float*)d_in[1];
    const int* agraph = (const int*)d_in[2];
    const int* bgraph = (const int*)d_in[3];
    const int* seq = (const int*)d_in[4];
    const float* Wi = (const float*)d_in[5];
    const float* Wh = (const float*)d_in[6];
    const float* Wo = (const float*)d_in[7];
    const float* Wob = (const float*)d_in[8];
    const float* embp = (const float*)d_in[9];
    const float* c0w = (const float*)d_in[10];
    const float* c0b = (const float*)d_in[11];
    const float* c1w = (const float*)d_in[12];
    const float* c1b = (const float*)d_in[13];
    const float* c2w = (const float*)d_in[14];
    const float* c2b = (const float*)d_in[15];
    const float* fc0w = (const float*)d_in[16];
    const float* fc0b = (const float*)d_in[17];
    const float* fc1w = (const float*)d_in[18];
    const float* fc1b = (const float*)d_in[19];
    const float* fc2w = (const float*)d_in[20];
    const float* fc2b = (const float*)d_in[21];

    float* ws = (float*)d_ws;
    float* binput = ws;                    // 2457600
    float* msgA = binput + 2457600;        // 2457600
    float* msgB = msgA + 2457600;          // 2457600
    float* x = msgB + 2457600;             // 51200
    ushort_t* u = (ushort_t*)(x + 51200);  // bf16 region
    ushort_t* act1 = u;                    // 128000*96  = 12288000
    ushort_t* act2 = act1 + 12288000;      // 128000*128 = 16384000
    ushort_t* Wb0 = act2 + 16384000;       // 4*12*512  = 24576
    ushort_t* Wb1 = Wb0 + 24576;           // 4*30*512  = 61440
    ushort_t* Wb2 = Wb1 + 61440;           // 8*56*512  = 229376

    // fused: weight swizzles + zero x (k_atom atomicAdd / conv2 atomicMax need zeros)
    k_prep_all<<<(PREP_T3 + 255) / 256, 256, 0, stream>>>(c0w, c1w, c2w, x, Wb0, Wb1, Wb2);

    // ---- MPNN ----
    k_bond_input<<<BATCH * NBB / BIPB, 256, 0, stream>>>(fbonds, Wi, binput, msgA);
    k_msg<<<BATCH * NBB / BPB, 256, 0, stream>>>(msgA, binput, bgraph, Wh, msgB);
    k_msg<<<BATCH * NBB / BPB, 256, 0, stream>>>(msgB, binput, bgraph, Wh, msgA);
    k_atom<<<BATCH * NA / APB, 256, 0, stream>>>(msgA, fatoms, agraph, Wo, Wob, x);

    // ---- protein tower (bf16 MFMA, 32x32x16; conv0 fuses embedding) ----
    k_conv0<<<dim3(8, 1, BATCH), 256, 0, stream>>>(seq, embp, Wb0, c0b, act1);
    k_conv1<<<dim3(8, 1, BATCH), 256, 0, stream>>>(act1, Wb1, c1b, act2);
    k_conv2<<<dim3(16, 1, BATCH), 256, 0, stream>>>(act2, Wb2, c2b, x);

    // ---- fused FC head ----
    k_fc<<<BATCH, 256, 0, stream>>>(x, fc0w, fc0b, fc1w, fc1b, fc2w, fc2b, (float*)d_out);
}